// Round 9
// baseline (299.855 us; speedup 1.0000x reference)
//
#include <hip/hip_runtime.h>
#include <cmath>

#define B_   128
#define H_   256
#define W_   256
#define WC_  129
#define L_   182
#define NG_  9     // column groups per image in pass2 (16 cols/group * 9 >= 129)
#define PI_F 3.14159265358979f

using half4 = __attribute__((ext_vector_type(4))) _Float16;
using half8 = __attribute__((ext_vector_type(8))) _Float16;

// ---------------------------------------------------------------------------
// Cross-lane DIF stage for 4 FFTs in the s = 4l+j layout, shared twiddles.
// Sub-FFT size N' = 8h; CT/ST = cos/sin(pi/(4h)).  (verified R7/R8, absmax 0)
// ---------------------------------------------------------------------------
__device__ __forceinline__ void stage4(float (&vr)[4][4], float (&vi)[4][4],
                                       int l, int h, float CT, float ST) {
  int i = l & (h - 1);
  float s, c;
  __sincosf(-PI_F * (float)i / (float)h, &s, &c);
  float wr[4], wi[4];
  wr[0] = c;                       wi[0] = s;
  wr[1] = c * CT + s * ST;         wi[1] = s * CT - c * ST;
  wr[2] = wr[1] * CT + wi[1] * ST; wi[2] = wi[1] * CT - wr[1] * ST;
  wr[3] = wr[2] * CT + wi[2] * ST; wi[3] = wi[2] * CT - wr[2] * ST;
  bool up = (l & h) != 0;
  float sgn = up ? -1.f : 1.f;
  #pragma unroll
  for (int f = 0; f < 4; ++f) {
    #pragma unroll
    for (int j = 0; j < 4; ++j) {
      float br = __shfl_xor(vr[f][j], h, 64);
      float bi = __shfl_xor(vi[f][j], h, 64);
      float tr = fmaf(sgn, vr[f][j], br);
      float ti = fmaf(sgn, vi[f][j], bi);
      float cc = up ? wr[j] : 1.f;
      float ss = up ? wi[j] : 0.f;
      vr[f][j] = tr * cc - ti * ss;
      vi[f][j] = tr * ss + ti * cc;
    }
  }
}

// Full 256-pt DIF FFT x4 (s = 4l+j layout). Output: storage s = 4l+j holds
// X[bitrev8(s)], i.e. frequency f = 64*br2(j) + br6(l).
__device__ __forceinline__ void fft256x4(float (&vr)[4][4], float (&vi)[4][4],
                                         int l) {
  stage4(vr, vi, l, 32, 0.9996988187f, 0.0245412285f);  // N'=256
  stage4(vr, vi, l, 16, 0.9987954562f, 0.0490676743f);  // N'=128
  stage4(vr, vi, l,  8, 0.9951847267f, 0.0980171403f);  // N'=64
  stage4(vr, vi, l,  4, 0.9807852804f, 0.1950903220f);  // N'=32
  stage4(vr, vi, l,  2, 0.9238795325f, 0.3826834324f);  // N'=16
  stage4(vr, vi, l,  1, 0.7071067812f, 0.7071067812f);  // N'=8
  #pragma unroll
  for (int f = 0; f < 4; ++f) {
    float u0r = vr[f][0] + vr[f][2], u0i = vi[f][0] + vi[f][2];
    float v0r = vr[f][0] - vr[f][2], v0i = vi[f][0] - vi[f][2];
    float u1r = vr[f][1] + vr[f][3], u1i = vi[f][1] + vi[f][3];
    float d1r = vr[f][1] - vr[f][3], d1i = vi[f][1] - vi[f][3];
    float v1r = d1i, v1i = -d1r;                 // (x1-x3)*(-i)
    vr[f][0] = u0r + u1r; vi[f][0] = u0i + u1i;
    vr[f][1] = u0r - u1r; vi[f][1] = u0i - u1i;
    vr[f][2] = v0r + v1r; vi[f][2] = v0i + v1i;
    vr[f][3] = v0r - v1r; vi[f][3] = v0i - v1i;
  }
}

__device__ __forceinline__ float4 luma4(float4 r, float4 g, float4 b) {
  float4 o;
  o.x = fmaf(0.299f, r.x, fmaf(0.587f, g.x, 0.114f * b.x));
  o.y = fmaf(0.299f, r.y, fmaf(0.587f, g.y, 0.114f * b.y));
  o.z = fmaf(0.299f, r.z, fmaf(0.587f, g.z, 0.114f * b.z));
  o.w = fmaf(0.299f, r.w, fmaf(0.587f, g.w, 0.114f * b.w));
  return o;
}

#define P1_STRIDE 259  // float2 LDS stride (measured cheap in R5: ~0 conflicts)

// Pass 1: luma + row-pair real FFT (R7-verified math). Output packed fp16:
// inter[b][k][pair] = half4{A.re,A.im,B.re,B.im}. Block 0 additionally builds
// the radial count histogram and zeroes the arrival counters (consumed by
// pass2 — safe by stream ordering).
__global__ __launch_bounds__(256) void pass1_kernel(
    const float* __restrict__ data, half4* __restrict__ interh,
    const int* __restrict__ radius, float* __restrict__ cnt,
    int* __restrict__ counters) {
  __shared__ float2 tile[16 * P1_STRIDE];
  __shared__ float lcnt[L_];
  int tid = threadIdx.x;
  bool blk0 = (blockIdx.x == 0);
  if (blk0 && tid < L_) lcnt[tid] = 0.f;
  int w = tid >> 6, l = tid & 63;
  int b = blockIdx.x >> 3;
  int rg = blockIdx.x & 7;
  int row0 = rg * 32;
  const float* img = data + ((size_t)b * 3) * (H_ * W_);
  float vr[4][4], vi[4][4];
  #pragma unroll
  for (int half = 0; half < 2; ++half) {
    float4 ra[2], ga[2], ba[2], rb[2], gb[2], bb[2];
    #pragma unroll
    for (int e = 0; e < 2; ++e) {
      int f = half * 2 + e;
      int rowA = row0 + 2 * (4 * w + f);
      const float* pA = img + (size_t)rowA * W_ + 4 * l;
      ra[e] = *(const float4*)(pA);
      ga[e] = *(const float4*)(pA + H_ * W_);
      ba[e] = *(const float4*)(pA + 2 * H_ * W_);
      rb[e] = *(const float4*)(pA + W_);
      gb[e] = *(const float4*)(pA + H_ * W_ + W_);
      bb[e] = *(const float4*)(pA + 2 * H_ * W_ + W_);
    }
    #pragma unroll
    for (int e = 0; e < 2; ++e) {
      int f = half * 2 + e;
      float4 A = luma4(ra[e], ga[e], ba[e]);
      float4 Bv = luma4(rb[e], gb[e], bb[e]);
      vr[f][0] = A.x; vr[f][1] = A.y; vr[f][2] = A.z; vr[f][3] = A.w;
      vi[f][0] = Bv.x; vi[f][1] = Bv.y; vi[f][2] = Bv.z; vi[f][3] = Bv.w;
    }
  }
  fft256x4(vr, vi, l);
  #pragma unroll
  for (int f = 0; f < 4; ++f) {
    int p = 4 * w + f;
    #pragma unroll
    for (int j = 0; j < 4; ++j)
      tile[p * P1_STRIDE + l + 64 * j] = make_float2(vr[f][j], vi[f][j]);
  }
  __syncthreads();
  // A(k) = (Z(k)+conj(Z(N-k)))/2 ; B(k) = (Z(k)-conj(Z(N-k)))/(2i)
  for (int fi = tid; fi < WC_ * 16; fi += 256) {
    int k = fi >> 4;
    int p = fi & 15;
    int q  = (int)(__brev((unsigned)k) >> 24);
    int qn = (int)(__brev((unsigned)((256 - k) & 255)) >> 24);
    int qs  = (q >> 2)  + 64 * (q & 3);   // swizzled LDS slot of storage q
    int qns = (qn >> 2) + 64 * (qn & 3);
    float2 Zk  = tile[p * P1_STRIDE + qs];
    float2 Znk = tile[p * P1_STRIDE + qns];
    half4 o;
    o[0] = (_Float16)(0.5f * (Zk.x + Znk.x));   // A.re
    o[1] = (_Float16)(0.5f * (Zk.y - Znk.y));   // A.im
    o[2] = (_Float16)(0.5f * (Zk.y + Znk.y));   // B.re
    o[3] = (_Float16)(0.5f * (Znk.x - Zk.x));   // B.im
    interh[((size_t)b * WC_ + k) * 128 + rg * 16 + p] = o;
  }
  if (blk0) {
    __syncthreads();
    int base = tid * 129;
    int end  = base + 129;
    if (end > H_ * WC_) end = H_ * WC_;
    for (int i = base; i < end; ++i) atomicAdd(&lcnt[radius[i]], 1.f);
    __syncthreads();
    if (tid < L_) cnt[tid] = lcnt[tid];
    if (tid < B_ + 1) counters[tid] = 0;
  }
}

// Pass 2 + fused loss: block = (image b, group g of 16 columns). 4 waves,
// each wave does 4 columns at once (fft256x4, s=4l+j layout, R8-verified
// binning map). Last-arriving block per image reduces the 9 partials into
// the per-sample loss; last image overall reduces to the scalar output.
__global__ __launch_bounds__(256) void pass2_kernel(
    const half8* __restrict__ interh8, const int* __restrict__ radius,
    const float* __restrict__ cnt, const float* __restrict__ mean,
    float* __restrict__ partial, float* __restrict__ lpart,
    int* __restrict__ counters, float* __restrict__ out) {
  __shared__ float lbins[L_];
  __shared__ float prof[L_];
  __shared__ float red[256];
  __shared__ int flag;
  int tid = threadIdx.x;
  int wv = tid >> 6, l = tid & 63;
  int b = blockIdx.x / NG_;
  int g = blockIdx.x - b * NG_;
  for (int i = tid; i < L_; i += 256) lbins[i] = 0.f;
  __syncthreads();

  const int amap[4] = {0, 2, 1, 3};                  // br2(j)
  const int m = (int)(__brev((unsigned)l) >> 26);    // br6(l)
  float vr[4][4], vi[4][4];
  int kc[4];
  #pragma unroll
  for (int ff = 0; ff < 4; ++ff) {
    int k = g * 16 + wv * 4 + ff;
    kc[ff] = k;
    int kr = (k < WC_) ? k : 0;
    half8 hx = interh8[((size_t)b * WC_ + kr) * 64 + l]; // pairs 2l,2l+1
    vr[ff][0] = (float)hx[0]; vi[ff][0] = (float)hx[1];  // row 4l   (A of 2l)
    vr[ff][1] = (float)hx[2]; vi[ff][1] = (float)hx[3];  // row 4l+1 (B of 2l)
    vr[ff][2] = (float)hx[4]; vi[ff][2] = (float)hx[5];  // row 4l+2
    vr[ff][3] = (float)hx[6]; vi[ff][3] = (float)hx[7];  // row 4l+3
  }
  fft256x4(vr, vi, l);
  #pragma unroll
  for (int ff = 0; ff < 4; ++ff) {
    if (kc[ff] < WC_) {
      #pragma unroll
      for (int j = 0; j < 4; ++j) {
        int frow = (amap[j] << 6) | m;
        int bin = radius[frow * WC_ + kc[ff]];
        float pw = vr[ff][j] * vr[ff][j] + vi[ff][j] * vi[ff][j];
        atomicAdd(&lbins[bin], 20.f * __logf(pw + 1e-8f));
      }
    }
  }
  __syncthreads();
  float* pp = partial + ((size_t)b * NG_ + g) * L_;
  for (int i = tid; i < L_; i += 256) pp[i] = lbins[i];

  // ---- arrival: last block of this image computes the per-sample loss ----
  if (tid == 0) {
    __threadfence();
    flag = (atomicAdd(&counters[b], 1) == NG_ - 1) ? 1 : 0;
  }
  __syncthreads();
  if (!flag) return;
  __threadfence();  // acquire: make other blocks' partials visible
  if (tid < L_) {
    const float* pb = partial + (size_t)b * NG_ * L_;
    float acc = 0.f;
    #pragma unroll
    for (int gg = 0; gg < NG_; ++gg) acc += pb[gg * L_ + tid];
    prof[tid] = acc / cnt[tid];
  }
  __syncthreads();
  red[tid] = (tid < L_) ? prof[tid] : INFINITY;
  __syncthreads();
  for (int s = 128; s > 0; s >>= 1) {
    if (tid < s) red[tid] = fminf(red[tid], red[tid + s]);
    __syncthreads();
  }
  float mn = red[0];
  __syncthreads();
  red[tid] = (tid < L_) ? (prof[tid] - mn) : -INFINITY;
  __syncthreads();
  for (int s = 128; s > 0; s >>= 1) {
    if (tid < s) red[tid] = fmaxf(red[tid], red[tid + s]);
    __syncthreads();
  }
  float mx = red[0];
  __syncthreads();
  red[tid] = (tid < L_) ? fabsf((prof[tid] - mn) / mx - mean[tid]) : 0.f;
  __syncthreads();
  for (int s = 128; s > 0; s >>= 1) {
    if (tid < s) red[tid] += red[tid + s];
    __syncthreads();
  }
  if (tid == 0) lpart[b] = red[0];

  // ---- global arrival: very last image sums the 128 losses ----
  if (tid == 0) {
    __threadfence();
    flag = (atomicAdd(&counters[B_], 1) == B_ - 1) ? 1 : 0;
  }
  __syncthreads();
  if (!flag) return;
  __threadfence();  // acquire lpart[]
  red[tid] = (tid < B_) ? lpart[tid] : 0.f;
  __syncthreads();
  for (int s = 128; s > 0; s >>= 1) {
    if (tid < s) red[tid] += red[tid + s];
    __syncthreads();
  }
  if (tid == 0) out[0] = red[0];
}

extern "C" void kernel_launch(void* const* d_in, const int* in_sizes, int n_in,
                              void* d_out, int out_size, void* d_ws, size_t ws_size,
                              hipStream_t stream) {
  const float* data   = (const float*)d_in[0];  // [128,3,256,256] f32
  const float* mean   = (const float*)d_in[1];  // [182] f32
  const int*   radius = (const int*)d_in[2];    // [256,129] i32
  float* out = (float*)d_out;                   // scalar f32

  half4* interh = (half4*)d_ws;                 // [B][WC][128] half4 = 16.9 MB
  size_t inter_bytes = (size_t)B_ * WC_ * 128 * sizeof(half4);
  float* partial  = (float*)((char*)d_ws + inter_bytes);  // [B][NG][L]
  float* cnt      = partial + (size_t)B_ * NG_ * L_;      // [L]
  float* lpart    = cnt + L_;                             // [B]
  int*   counters = (int*)(lpart + B_);                   // [B+1]

  pass1_kernel<<<B_ * 8, 256, 0, stream>>>(data, interh, radius, cnt, counters);
  pass2_kernel<<<B_ * NG_, 256, 0, stream>>>((const half8*)interh, radius, cnt,
                                             mean, partial, lpart, counters, out);
}